// Round 7
// baseline (446.798 us; speedup 1.0000x reference)
//
#include <hip/hip_runtime.h>
#include <cstdint>
#include <cstdio>

#define DEVI __device__ __forceinline__

constexpr int TOKS = 8192;
constexpr int HID  = 1024;
constexpr int INTR = 2048;
constexpr int SINT = 1024;
constexpr int NEXP = 8;
constexpr int MAXSLOT = 17408;   // 16384 assignments + 8*127 padding, rounded up

typedef __bf16 bf16x8 __attribute__((ext_vector_type(8)));
typedef float  f32x4  __attribute__((ext_vector_type(4)));

DEVI unsigned short f2bf(float f) {
  unsigned int u = __float_as_uint(f);
  u += 0x7FFFu + ((u >> 16) & 1u);   // round-to-nearest-even
  return (unsigned short)(u >> 16);
}

DEVI float bf2f(unsigned short h) {
  return __uint_as_float((unsigned int)h << 16);
}

// async global->LDS, 16B per lane. LDS dest = wave-uniform base + lane*16
// (our per-thread tid*16B dest is exactly that); global addr per-lane (gather OK).
DEVI void gl_lds16(const unsigned short* g, unsigned short* l) {
  __attribute__((address_space(1))) uint32_t* gp =
      (__attribute__((address_space(1))) uint32_t*)(uintptr_t)g;
  __attribute__((address_space(3))) uint32_t* lp =
      (__attribute__((address_space(3))) uint32_t*)(uint32_t)(uintptr_t)l;
  __builtin_amdgcn_global_load_lds(gp, lp, 16, 0, 0);
}

// exact-gelu via Abramowitz-Stegun 7.1.26 erf (|err| <= 1.5e-7), ~14 VALU ops.
DEVI float gelu_fast(float x) {
  const float z = fabsf(x) * 0.70710678118654752f;
  const float t = __builtin_amdgcn_rcpf(1.0f + 0.3275911f * z);
  float p = 1.061405429f;
  p = p * t - 1.453152027f;
  p = p * t + 1.421413741f;
  p = p * t - 0.284496736f;
  p = p * t + 0.254829592f;
  const float e = __builtin_amdgcn_exp2f(-z * z * 1.4426950408889634f);  // exp(-z^2)
  float erfz = 1.0f - p * t * e;     // erf(|z|)
  erfz = copysignf(erfz, x);
  return 0.5f * x * (1.0f + erfz);
}

// bijective XCD-chunked remap (m204): XCD k (= bid%8 dispatch heuristic) owns a
// contiguous chunk of the active tile space -> per-XCD L2 keeps one B-panel hot.
DEVI int xcd_chunk_map(int bid, int total) {
  const int q = total >> 3, r = total & 7;
  const int x = bid & 7, i = bid >> 3;
  return (x < r ? x * (q + 1) : r * (q + 1) + (x - r) * q) + i;
}

// ---------------- fused [router | fp32->bf16 weight convert] in ONE launch ----------------
// blocks [0, TOKS/4)        : router (fp32 logits, top-2, softmax; emits bf16 x)
// blocks [TOKS/4, TOKS/4+NW): grid-stride convert of the 4 weight tensors
__global__ __launch_bounds__(256) void k_fr(
    const float* __restrict__ x, const float* __restrict__ wg,
    unsigned short* __restrict__ xb,
    int* __restrict__ rec_e, float2* __restrict__ rec_g,
    const float* __restrict__ s0, unsigned short* __restrict__ d0, int n0,
    const float* __restrict__ s1, unsigned short* __restrict__ d1, int n1,
    const float* __restrict__ s2, unsigned short* __restrict__ d2, int n2,
    const float* __restrict__ s3, unsigned short* __restrict__ d3, int n3) {
  if (blockIdx.x < TOKS / 4) {
    // ---------------- router ----------------
    const int wave = threadIdx.x >> 6;
    const int lane = threadIdx.x & 63;
    const int t = blockIdx.x * 4 + wave;

    float4 xv[4];
    const float4* x4 = (const float4*)(x + (size_t)t * HID);
#pragma unroll
    for (int j = 0; j < 4; ++j) xv[j] = x4[j * 64 + lane];

    ushort4* xb4 = (ushort4*)(xb + (size_t)t * HID);
#pragma unroll
    for (int j = 0; j < 4; ++j) {
      float4 v = xv[j];
      ushort4 o; o.x = f2bf(v.x); o.y = f2bf(v.y); o.z = f2bf(v.z); o.w = f2bf(v.w);
      xb4[j * 64 + lane] = o;
    }

    float lg[NEXP];
#pragma unroll
    for (int e = 0; e < NEXP; ++e) {
      const float4* w4 = (const float4*)(wg + (size_t)e * HID);
      float s = 0.f;
#pragma unroll
      for (int j = 0; j < 4; ++j) {
        float4 a = xv[j], b = w4[j * 64 + lane];
        s += a.x * b.x + a.y * b.y + a.z * b.z + a.w * b.w;
      }
      lg[e] = s;
    }
#pragma unroll
    for (int e = 0; e < NEXP; ++e)
#pragma unroll
      for (int off = 32; off > 0; off >>= 1) lg[e] += __shfl_xor(lg[e], off);

    if (lane == 0) {
      int b0 = 0; float v0 = lg[0];
      for (int e = 1; e < NEXP; ++e) if (lg[e] > v0) { v0 = lg[e]; b0 = e; }
      int b1 = -1; float v1 = -1e30f;
      for (int e = 0; e < NEXP; ++e) if (e != b0 && lg[e] > v1) { v1 = lg[e]; b1 = e; }
      const float d = expf(v1 - v0);
      const float g0 = 1.f / (1.f + d);
      const float g1 = d / (1.f + d);
      rec_e[t] = b0 | (b1 << 16);
      rec_g[t] = make_float2(g0, g1);
    }
  } else {
    // ---------------- weight convert (grid-stride over 4 arrays) ----------------
    const int nb = gridDim.x - TOKS / 4;
    const int ntot = n0 + n1 + n2 + n3;
    int i = (blockIdx.x - TOKS / 4) * 256 + threadIdx.x;
    const int stride = nb * 256;
    for (; i < ntot; i += stride) {
      int j = i;
      const float* s; unsigned short* d;
      if (j < n0) { s = s0; d = d0; }
      else if ((j -= n0) < n1) { s = s1; d = d1; }
      else if ((j -= n1) < n2) { s = s2; d = d2; }
      else { j -= n2; s = s3; d = d3; }
      float4 v = ((const float4*)s)[j];
      ushort4 o;
      o.x = f2bf(v.x); o.y = f2bf(v.y); o.z = f2bf(v.z); o.w = f2bf(v.w);
      ((ushort4*)d)[j] = o;
    }
  }
}

// ---------------- sort: single-block fused count+scan+assign ----------------
// 1024 threads, 8 tokens each. 4-way sub-histogram LDS atomics (contention /4),
// inline scan builds cnt/offs + tile tables, final slots written directly:
// rec_s[t] = s0 | s1<<16 (slots < 17408 < 2^16). tok[slot] = t.
// offs[0..8]  : 128-padded slot offsets
// offs[16..24]: tb0 cumulative tiles for fc   (m-tiles * INTR/128)
// offs[32..40]: tb1 cumulative tiles for proj (m-tiles * HID/128)
__global__ __launch_bounds__(1024) void k_sort(
    const int* __restrict__ rec_e, int* __restrict__ rec_s,
    int* __restrict__ cnt, int* __restrict__ offs, int* __restrict__ tok) {
  __shared__ int hist[4][NEXP];
  __shared__ int base[4][NEXP];
  const int tid = threadIdx.x;
  const int sub = tid & 3;
  if (tid < 32) ((int*)hist)[tid] = 0;
  __syncthreads();
  int e0[8], e1[8], r0[8], r1[8];
#pragma unroll
  for (int i = 0; i < 8; ++i) {
    const int t = i * 1024 + tid;
    const int ee = rec_e[t];
    e0[i] = ee & 0xffff; e1[i] = ee >> 16;
    r0[i] = atomicAdd(&hist[sub][e0[i]], 1);
    r1[i] = atomicAdd(&hist[sub][e1[i]], 1);
  }
  __syncthreads();
  if (tid == 0) {
    int* tb0 = offs + 16;
    int* tb1 = offs + 32;
    int o = 0, t0 = 0, t1 = 0;
    tb0[0] = 0; tb1[0] = 0;
    for (int e = 0; e < NEXP; ++e) {
      int c = 0;
#pragma unroll
      for (int j = 0; j < 4; ++j) { base[j][e] = o + c; c += hist[j][e]; }
      cnt[e] = c;
      offs[e] = o;
      const int mt = (c + 127) >> 7;
      o += mt << 7;
      t0 += mt * (INTR / 128);
      t1 += mt * (HID / 128);
      tb0[e + 1] = t0;
      tb1[e + 1] = t1;
    }
    offs[NEXP] = o;
  }
  __syncthreads();
#pragma unroll
  for (int i = 0; i < 8; ++i) {
    const int t = i * 1024 + tid;
    const int S0 = base[sub][e0[i]] + r0[i];
    const int S1 = base[sub][e1[i]] + r1[i];
    rec_s[t] = S0 | (S1 << 16);
    tok[S0] = t;
    tok[S1] = t;
  }
}

// ---------------- fused GEMM pair: C[m,n] = sum_k A[m,k]*B[n,k]  (B row-major [N,K]) ------
// Round-3-verified inner loop: 128x128 tile, BK=64, 256 thr = 4 waves (2Mx2N), 64KB LDS
// double-buffer -> 2 blocks/CU. 2-phase pipeline: stage(next) issued BEFORE compute(cur);
// one __syncthreads per K-step. 8-chunk XOR swizzle on BOTH staging source and ds_read
// addr (verified 0 conflicts). Flattened 1-D grid with XCD-chunked remap; expert tiles
// [0, expTotal) and shared tiles [expTotal, total) in ONE launch.
// PHASE 0 (FC, gelu): expert {A=xb gathered via tok, B=wfc, out=h, N=2048,K=1024}
//                     shared {A=xb, B=wfs, out=hs, N=1024,K=1024}
// PHASE 1 (PROJ,raw): expert {A=h (slot rows), B=wpj, out=Y, N=1024,K=2048}
//                     shared {A=hs, B=wps, out=Ys, N=1024,K=1024}
template <int PHASE>
__global__ __launch_bounds__(256, 2) void k_gemmF(
    const unsigned short* __restrict__ Ae,
    const unsigned short* __restrict__ Be,
    unsigned short* __restrict__ He,
    const unsigned short* __restrict__ Ash,
    const unsigned short* __restrict__ Bsh,
    unsigned short* __restrict__ Hsh,
    const int* __restrict__ cnt,
    const int* __restrict__ offs,
    const int* __restrict__ tok) {
  constexpr int SH_TILES = (TOKS / 128) * 8;   // shared N=1024 -> 8 n-tiles; 512 tiles

  const int* tb = offs + ((PHASE == 0) ? 16 : 32);
  const int expTotal = tb[8];
  const int total = expTotal + SH_TILES;
  int bid = blockIdx.x;
  if (bid >= total) return;                    // tail overflow blocks exit fast
  bid = xcd_chunk_map(bid, total);

  const unsigned short *A, *B;
  unsigned short* Hout;
  int count, gOff = 0, m0, n0, K, N;
  bool gather = false;
  if (bid < expTotal) {
    constexpr int NT_SHIFT = (PHASE == 0) ? 4 : 3;   // log2(N/128)
    int e = 0;
    while (bid >= tb[e + 1]) ++e;              // <=8 scalar iters
    const int local = bid - tb[e];
    count = cnt[e];
    const int off = offs[e];
    m0 = (local >> NT_SHIFT) << 7;             // nt-fastest within expert
    n0 = (local & ((1 << NT_SHIFT) - 1)) << 7;
    K = (PHASE == 0) ? HID : INTR;
    N = (PHASE == 0) ? INTR : HID;
    if (PHASE == 0) { A = Ae; gather = true; gOff = off; }   // gather x rows via tok
    else            { A = Ae + (size_t)off * K; }            // slot rows of h
    B = Be + (size_t)e * (size_t)N * K;
    Hout = He + (size_t)off * N;
  } else {
    const int local = bid - expTotal;
    count = TOKS;
    m0 = (local >> 3) << 7;
    n0 = (local & 7) << 7;
    K = (PHASE == 0) ? HID : SINT;
    N = (PHASE == 0) ? SINT : HID;
    A = Ash; B = Bsh; Hout = Hsh;
  }

  __shared__ alignas(16) unsigned short As[2][128 * 64];   // 32KB
  __shared__ alignas(16) unsigned short Bs[2][128 * 64];   // 32KB

  const int tid = threadIdx.x;

  // ---- staging: 4 rounds of 32 rows each; source chunk pre-swizzled, LDS dest linear ----
  const int srow = tid >> 3;                  // 0..31
  const int schunk = tid & 7;                 // 16B chunk within 128B row
  const unsigned short* gA[4];
  const unsigned short* gB[4];
#pragma unroll
  for (int r = 0; r < 4; ++r) {
    const int gr = r * 32 + srow;             // row within tile (0..127)
    int mr = m0 + gr; if (mr > count - 1) mr = count - 1;   // clamp tail rows
    const int row = gather ? tok[gOff + mr] : mr;
    const int sc = ((schunk ^ (gr & 7)) & 7) * 8;
    gA[r] = A + (size_t)row * (size_t)K + sc;
    gB[r] = B + (size_t)(n0 + gr) * (size_t)K + sc;
  }

  // ---- ds_read byte offsets (swizzled); subtile s flips bit 6 ----
  const int wid = tid >> 6;
  const int lane = tid & 63;
  const int wr = wid >> 1;                    // 0..1
  const int wc = wid & 1;                     // 0..1
  const int fm = lane & 15;
  const int fq = lane >> 4;
  int aOff[4], bOff[4];
#pragma unroll
  for (int i = 0; i < 4; ++i) {
    const int row = wr * 64 + i * 16 + fm;
    aOff[i] = row * 128 + ((fq ^ (row & 7)) * 16);
  }
#pragma unroll
  for (int j = 0; j < 4; ++j) {
    const int row = wc * 64 + j * 16 + fm;
    bOff[j] = row * 128 + ((fq ^ (row & 7)) * 16);
  }

  auto stage = [&](int buf, int k0) {
#pragma unroll
    for (int r = 0; r < 4; ++r)
      gl_lds16(gA[r] + k0, &As[buf][r * 2048 + tid * 8]);
#pragma unroll
    for (int r = 0; r < 4; ++r)
      gl_lds16(gB[r] + k0, &Bs[buf][r * 2048 + tid * 8]);
  };

  f32x4 acc[4][4] = {};

  stage(0, 0);
  __syncthreads();

  int cur = 0;
  for (int k0 = 0; k0 < K; k0 += 64) {
    const bool more = (k0 + 64 < K);
    if (more) stage(cur ^ 1, k0 + 64);        // issue next-tile loads FIRST

    const char* aBase = (const char*)&As[cur][0];
    const char* bBase = (const char*)&Bs[cur][0];
    __builtin_amdgcn_s_setprio(1);
#pragma unroll
    for (int s = 0; s < 2; ++s) {             // two K=32 subtiles
      bf16x8 af[4], bfr[4];
#pragma unroll
      for (int i = 0; i < 4; ++i)
        af[i] = *(const bf16x8*)(aBase + (aOff[i] ^ (s << 6)));
#pragma unroll
      for (int j = 0; j < 4; ++j)
        bfr[j] = *(const bf16x8*)(bBase + (bOff[j] ^ (s << 6)));
#pragma unroll
      for (int i = 0; i < 4; ++i)
#pragma unroll
        for (int j = 0; j < 4; ++j)
          acc[i][j] = __builtin_amdgcn_mfma_f32_16x16x32_bf16(af[i], bfr[j], acc[i][j], 0, 0, 0);
    }
    __builtin_amdgcn_s_setprio(0);

    if (more) { __syncthreads(); cur ^= 1; }  // one barrier (w/ vmcnt drain) per K-step
  }

  // ---- epilogue: C/D row = fq*4 + reg, col = lane&15 ----
  constexpr bool GELU = (PHASE == 0);
#pragma unroll
  for (int i = 0; i < 4; ++i) {
#pragma unroll
    for (int rr = 0; rr < 4; ++rr) {
      const int m = m0 + wr * 64 + i * 16 + fq * 4 + rr;
      if (m < count) {                        // guard pad rows
        unsigned short* orow = Hout + (size_t)m * N + (n0 + wc * 64 + fm);
#pragma unroll
        for (int j = 0; j < 4; ++j) {
          const float v = acc[i][j][rr];
          orow[j * 16] = f2bf(GELU ? gelu_fast(v) : v);
        }
      }
    }
  }
}

// ---------------- combine: out[t] = g0*Y[s0] + g1*Y[s1] + Ys[t] ----------------
__global__ __launch_bounds__(256) void k_combine(
    const unsigned short* __restrict__ Y,   // [MAXSLOT, HID] bf16
    const unsigned short* __restrict__ Ys,  // [TOKS, HID] bf16
    const int* __restrict__ rec_s, const float2* __restrict__ rec_g,
    float* __restrict__ out) {
  const int t = blockIdx.x;
  const int rs = rec_s[t];
  const float2 g = rec_g[t];
  const int s0 = rs & 0xffff;
  const int s1 = (rs >> 16) & 0xffff;
  const int c = threadIdx.x * 4;
  ushort4 a = *(const ushort4*)&Y[(size_t)s0 * HID + c];
  ushort4 b = *(const ushort4*)&Y[(size_t)s1 * HID + c];
  ushort4 s = *(const ushort4*)&Ys[(size_t)t * HID + c];
  float4 o;
  o.x = g.x * bf2f(a.x) + g.y * bf2f(b.x) + bf2f(s.x);
  o.y = g.x * bf2f(a.y) + g.y * bf2f(b.y) + bf2f(s.y);
  o.z = g.x * bf2f(a.z) + g.y * bf2f(b.z) + bf2f(s.z);
  o.w = g.x * bf2f(a.w) + g.y * bf2f(b.w) + bf2f(s.w);
  *(float4*)&out[(size_t)t * HID + c] = o;
}

extern "C" void kernel_launch(void* const* d_in, const int* in_sizes, int n_in,
                              void* d_out, int out_size, void* d_ws, size_t ws_size,
                              hipStream_t stream) {
  const float* x   = (const float*)d_in[0];
  const float* wg  = (const float*)d_in[1];
  const float* wfc = (const float*)d_in[2];
  const float* wpj = (const float*)d_in[3];
  const float* wfs = (const float*)d_in[4];
  const float* wps = (const float*)d_in[5];
  float* out = (float*)d_out;
  char* ws = (char*)d_ws;

  // workspace layout (bytes)
  constexpr size_t OFF_XB   = 0;                                  // 16.78 MB
  constexpr size_t OFF_WFC  = OFF_XB   + (size_t)TOKS * HID * 2;  // 33.55 MB
  constexpr size_t OFF_WPJ  = OFF_WFC  + (size_t)NEXP * INTR * HID * 2;  // 33.55 MB
  constexpr size_t OFF_WFS  = OFF_WPJ  + (size_t)NEXP * HID * INTR * 2;  // 2.10 MB
  constexpr size_t OFF_WPS  = OFF_WFS  + (size_t)SINT * HID * 2;  // 2.10 MB
  constexpr size_t OFF_H    = OFF_WPS  + (size_t)HID * SINT * 2;  // 71.30 MB
  constexpr size_t OFF_HS   = OFF_H    + (size_t)MAXSLOT * INTR * 2;  // 16.78 MB
  constexpr size_t OFF_Y    = OFF_HS   + (size_t)TOKS * SINT * 2;  // 35.65 MB
  constexpr size_t OFF_YS   = OFF_Y    + (size_t)MAXSLOT * HID * 2;  // 16.78 MB
  constexpr size_t OFF_CNT  = OFF_YS   + (size_t)TOKS * HID * 2;
  constexpr size_t OFF_OFFS = OFF_CNT  + 32;
  constexpr size_t OFF_RECE = OFF_OFFS + 256;   // offs[0..8] + tb0[16..24] + tb1[32..40]
  constexpr size_t OFF_RECS = OFF_RECE + (size_t)TOKS * 4;
  constexpr size_t OFF_RECG = OFF_RECS + (size_t)TOKS * 4;
  constexpr size_t OFF_TOK  = OFF_RECG + (size_t)TOKS * 8;
  // total ~229 MB

  unsigned short* xb   = (unsigned short*)(ws + OFF_XB);
  unsigned short* wfcb = (unsigned short*)(ws + OFF_WFC);
  unsigned short* wpjb = (unsigned short*)(ws + OFF_WPJ);
  unsigned short* wfsb = (unsigned short*)(ws + OFF_WFS);
  unsigned short* wpsb = (unsigned short*)(ws + OFF_WPS);
  unsigned short* h    = (unsigned short*)(ws + OFF_H);
  unsigned short* hs   = (unsigned short*)(ws + OFF_HS);
  unsigned short* Y    = (unsigned short*)(ws + OFF_Y);
  unsigned short* Ys   = (unsigned short*)(ws + OFF_YS);
  int*    cnt   = (int*)(ws + OFF_CNT);
  int*    offs  = (int*)(ws + OFF_OFFS);
  int*    rec_e = (int*)(ws + OFF_RECE);
  int*    rec_s = (int*)(ws + OFF_RECS);
  float2* rec_g = (float2*)(ws + OFF_RECG);
  int*    tok   = (int*)(ws + OFF_TOK);

  // fused router + weight convert: blocks [0,2048) router, [2048,4096) convert
  k_fr<<<TOKS / 4 + 2048, 256, 0, stream>>>(
      x, wg, xb, rec_e, rec_g,
      wfc, wfcb, NEXP * INTR * HID / 4,
      wpj, wpjb, NEXP * HID * INTR / 4,
      wfs, wfsb, SINT * HID / 4,
      wps, wpsb, HID * SINT / 4);

  // fused count+scan+assign (single block; writes cnt/offs/tile tables/slots/tok)
  k_sort<<<1, 1024, 0, stream>>>(rec_e, rec_s, cnt, offs, tok);

  // worst-case flattened grids: expert tiles (sum ceil(c_e/128) <= 136) + 512 shared tiles
  constexpr int GRID_FC = 136 * (INTR / 128) + (TOKS / 128) * 8;   // 2176 + 512 = 2688
  constexpr int GRID_PJ = 136 * (HID  / 128) + (TOKS / 128) * 8;   // 1088 + 512 = 1600

  // fused FC: expert fc (gather, N=2048,K=1024 -> h) + shared fc (N=1024,K=1024 -> hs)
  k_gemmF<0><<<GRID_FC, 256, 0, stream>>>(xb, wfcb, h, xb, wfsb, hs, cnt, offs, tok);
  // fused PROJ: expert proj (N=1024,K=2048 -> Y) + shared proj (N=1024,K=1024 -> Ys)
  k_gemmF<1><<<GRID_PJ, 256, 0, stream>>>(h, wpjb, Y, hs, wpsb, Ys, cnt, offs, tok);

  // final combine: out[t] = g0*Y[s0] + g1*Y[s1] + Ys[t]
  k_combine<<<TOKS, 256, 0, stream>>>(Y, Ys, rec_s, rec_g, out);
}